// Round 1
// baseline (106.345 us; speedup 1.0000x reference)
//
#include <hip/hip_runtime.h>
#include <cmath>

namespace {

constexpr int kDim = 5;
constexpr int kSave = 64;
constexpr int kTraj = 16;      // trajectories per block (= MFMA M)
constexpr int kThreads = 256;  // 4 waves; wave w owns neuron tile [16w,16w+16)
constexpr int kMaxSteps = 64;
constexpr int HS = 72;         // f16 stride: activation planes (144 B)
constexpr int SD = 8;          // f32 stride: small state rows
constexpr int OS = kTraj * kDim;  // sOut save-row stride (80 f32); traj stride 5
                                  // => interp writes hit 16 distinct banks

typedef _Float16 half8 __attribute__((ext_vector_type(8)));
typedef float f32x4 __attribute__((ext_vector_type(4)));

__device__ __forceinline__ float softplusf(float x) {
  return fmaxf(x, 0.0f) + __logf(1.0f + __expf(-fabsf(x)));
}

// lgkm-only workgroup barrier. Legal because the stepping loop touches ONLY
// LDS (output accumulates in sOut; no global loads/stores between barriers),
// so __syncthreads' vmcnt(0) drain is pure overhead. Producer side: drain DS
// ops BEFORE signaling arrival; empty asm after stops loads sinking above.
__device__ __forceinline__ void barrier_lgkm() {
  asm volatile("s_waitcnt lgkmcnt(0)" ::: "memory");
  __builtin_amdgcn_s_barrier();
  asm volatile("" ::: "memory");
}

struct FragsA { half8 h0a, h1a, l0a, l1a; };

__global__ __launch_bounds__(kThreads, 1)
void node_tsit5_kernel(const float* __restrict__ gy0,
                       const float* __restrict__ gte,
                       const float* __restrict__ gW1, const float* __restrict__ gb1,
                       const float* __restrict__ gW2, const float* __restrict__ gb2,
                       const float* __restrict__ gW3, const float* __restrict__ gb3,
                       const float* __restrict__ gW4, const float* __restrict__ gb4,
                       float* __restrict__ out) {
  const float A21 = 0.161f;
  const float A31 = -0.008480655492356989f, A32 = 0.335480655492357f;
  const float A41 = 2.8971530571054935f, A42 = -6.359448489975075f, A43 = 4.3622954328695815f;
  const float A51 = 5.325864828439257f, A52 = -11.748883564062828f, A53 = 7.4955393428898365f,
              A54 = -0.09249506636175525f;
  const float A61 = 5.86145544294642f, A62 = -12.92096931784711f, A63 = 8.159367898576159f,
              A64 = -0.071584973281401f, A65 = -0.028269050394068383f;
  const float B1 = 0.09646076681806523f, B2 = 0.01f, B3 = 0.4798896504144996f,
              B4 = 1.379008574103742f, B5 = -3.290069515436081f, B6 = 2.324710524099774f;
  const float E1 = -0.00178001105222577714f, E2 = -0.0008164344596567469f,
              E3 = 0.007880878010261995f, E4 = -0.1447110071732629f, E5 = 0.5823571654525552f,
              E6 = -0.45808210592918697f, E7 = 0.015151515151515152f;

  __shared__ __align__(16) _Float16 h0[kTraj * HS], l0[kTraj * HS];
  __shared__ __align__(16) _Float16 h1[kTraj * HS], l1[kTraj * HS];
  __shared__ __align__(16) _Float16 h2[kTraj * HS], l2[kTraj * HS];
  __shared__ float sTe[kSave];
  __shared__ float sY[kTraj * SD], sYN[kTraj * SD], sK1[kTraj * SD], sK7[kTraj * SD];
  __shared__ float ctT[kTraj], ctH[kTraj], ctN[kTraj], ctO[kTraj];
  __shared__ __align__(16) float sOut[kSave * OS];  // [save][traj][dim], 20 KB

  const int tid = threadIdx.x;
  const int bid = blockIdx.x;
  const int w = tid >> 6;          // wave id = neuron tile
  const int ln = tid & 63;
  const int quad = ln >> 4;
  const int col = ln & 15;
  const int row0 = quad * 4;       // this lane's C-layout trajectories: row0+r
  const int nn = (w << 4) | col;
  const bool cact = col < kDim;    // C-lane carries dim d = col
  const bool w0 = (w == 0);

  // ---- one-time: weight B-frags + biases + fused M = W1*W4 ----
  half8 w2h[2], w3h[2], w4h[2], mfh[2];
  float w1r[kDim];
  #pragma unroll
  for (int d = 0; d < kDim; ++d) w1r[d] = gW1[nn * 5 + d];
  #pragma unroll
  for (int kf = 0; kf < 2; ++kf)
    #pragma unroll
    for (int j = 0; j < 8; ++j) {
      int kk2 = kf * 32 + quad * 8 + j;
      w2h[kf][j] = (_Float16)gW2[nn * 64 + kk2];
      w3h[kf][j] = (_Float16)gW3[nn * 64 + kk2];
      w4h[kf][j] = cact ? (_Float16)gW4[col * 64 + kk2] : (_Float16)0.0f;
      float m = 0.0f;
      #pragma unroll
      for (int d = 0; d < kDim; ++d) m = fmaf(w1r[d], gW4[d * 64 + kk2], m);
      mfh[kf][j] = (_Float16)m;
    }
  const float c1 = gb1[nn], c2 = gb2[nn], c3 = gb3[nn];
  const float c4 = cact ? gb4[col] : 0.0f;   // => k cols>=5 are exactly 0
  float cu = 0.0f;                            // (W1*b4)[nn]
  #pragma unroll
  for (int d = 0; d < kDim; ++d) cu = fmaf(w1r[d], gb4[d], cu);

  // ---- init LDS ----
  if (tid < kSave) sTe[tid] = gte[tid];
  if (tid < kTraj * kDim) {   // sY for the y0 output fill
    int t = tid & 15, d = tid >> 4;
    sY[t * SD + d] = gy0[(size_t)(bid * kTraj + t) * kDim + d];
  }
  {  // zero the LDS output accumulator (replaces global zero-fill)
    f32x4 zz = {0.f, 0.f, 0.f, 0.f};
    f32x4* z4 = (f32x4*)sOut;
    for (int i = tid; i < (kSave * OS) / 4; i += kThreads) z4[i] = zz;
  }

  // y-state (replicated across waves) + p_y = W1*y + b1 (per wave tile, f32)
  f32x4 syr = {0, 0, 0, 0}, synr = {0, 0, 0, 0}, kk[7], uu[7], p_y;
  #pragma unroll
  for (int r = 0; r < 4; ++r) {
    const float* yr = gy0 + (size_t)(bid * kTraj + row0 + r) * kDim;
    float acc = c1;
    #pragma unroll
    for (int d = 0; d < kDim; ++d) acc = fmaf(w1r[d], yr[d], acc);
    p_y[r] = acc;
    if (cact) syr[r] = yr[col];
  }
  barrier_lgkm();

  const float t0v = sTe[0];
  const float t1v = sTe[kSave - 1];

  // saves at/before t0 get y0 (same-lane overwrite later -> program order)
  {
    int tt = tid & 15, gg = tid >> 4;
    float yv[kDim];
    #pragma unroll
    for (int d = 0; d < kDim; ++d) yv[d] = sY[tt * SD + d];
    #pragma unroll
    for (int q = 0; q < 4; ++q) {
      int n = 4 * gg + q;
      if (sTe[n] <= t0v + 1e-6f) {
        float* op = sOut + n * OS + tt * kDim;
        #pragma unroll
        for (int d = 0; d < kDim; ++d) op[d] = yv[d];
      }
    }
  }

  // ---- stage A: softplus(pre1) -> h0/l0 (no barrier; caller barriers) ----
  auto stageA = [&](f32x4 pre1) {
    #pragma unroll
    for (int r = 0; r < 4; ++r) {
      float s = softplusf(pre1[r]);
      _Float16 hi = (_Float16)s;
      h0[(row0 + r) * HS + nn] = hi;
      l0[(row0 + r) * HS + nn] = (_Float16)(s - (float)hi);
    }
  };

  // ---- L2 A-fragment load (issue ASAP after the barrier that publishes h0) --
  auto loadA0 = [&]() {
    FragsA f;
    f.h0a = *(const half8*)(h0 + col * HS + quad * 8);
    f.h1a = *(const half8*)(h0 + col * HS + 32 + quad * 8);
    f.l0a = *(const half8*)(l0 + col * HS + quad * 8);
    f.l1a = *(const half8*)(l0 + col * HS + 32 + quad * 8);
    return f;
  };

  // ---- evalR: [L2 | b2 | L3 | b3 | final]; takes preloaded L2 A-frags ----
  auto evalR = [&](FragsA f, f32x4& kOut, f32x4& uOut) {
    {  // L2: f (from h0/l0) -> h1/l1
      f32x4 a = {c2, c2, c2, c2};
      f32x4 b = {0, 0, 0, 0};
      a = __builtin_amdgcn_mfma_f32_16x16x32_f16(f.h0a, w2h[0], a, 0, 0, 0);
      b = __builtin_amdgcn_mfma_f32_16x16x32_f16(f.l0a, w2h[0], b, 0, 0, 0);
      a = __builtin_amdgcn_mfma_f32_16x16x32_f16(f.h1a, w2h[1], a, 0, 0, 0);
      b = __builtin_amdgcn_mfma_f32_16x16x32_f16(f.l1a, w2h[1], b, 0, 0, 0);
      a += b;
      #pragma unroll
      for (int r = 0; r < 4; ++r) {
        float s = softplusf(a[r]);
        _Float16 hi = (_Float16)s;
        h1[(row0 + r) * HS + nn] = hi;
        l1[(row0 + r) * HS + nn] = (_Float16)(s - (float)hi);
      }
    }
    barrier_lgkm();   // b2
    {  // L3: h1/l1 -> h2/l2
      half8 ah0 = *(const half8*)(h1 + col * HS + quad * 8);
      half8 ah1 = *(const half8*)(h1 + col * HS + 32 + quad * 8);
      half8 al0 = *(const half8*)(l1 + col * HS + quad * 8);
      half8 al1 = *(const half8*)(l1 + col * HS + 32 + quad * 8);
      f32x4 a = {c3, c3, c3, c3};
      f32x4 b = {0, 0, 0, 0};
      a = __builtin_amdgcn_mfma_f32_16x16x32_f16(ah0, w3h[0], a, 0, 0, 0);
      b = __builtin_amdgcn_mfma_f32_16x16x32_f16(al0, w3h[0], b, 0, 0, 0);
      a = __builtin_amdgcn_mfma_f32_16x16x32_f16(ah1, w3h[1], a, 0, 0, 0);
      b = __builtin_amdgcn_mfma_f32_16x16x32_f16(al1, w3h[1], b, 0, 0, 0);
      a += b;
      #pragma unroll
      for (int r = 0; r < 4; ++r) {
        float s = softplusf(a[r]);
        _Float16 hi = (_Float16)s;
        h2[(row0 + r) * HS + nn] = hi;
        l2[(row0 + r) * HS + nn] = (_Float16)(s - (float)hi);
      }
    }
    barrier_lgkm();   // b3
    {  // final: k = W4*h3 + b4 (cols<5) and u = M*h3 + W1*b4 (this tile)
      half8 ah0 = *(const half8*)(h2 + col * HS + quad * 8);
      half8 ah1 = *(const half8*)(h2 + col * HS + 32 + quad * 8);
      half8 al0 = *(const half8*)(l2 + col * HS + quad * 8);
      half8 al1 = *(const half8*)(l2 + col * HS + 32 + quad * 8);
      f32x4 ka = {c4, c4, c4, c4};
      f32x4 kb = {0, 0, 0, 0};
      f32x4 ua = {cu, cu, cu, cu};
      f32x4 ub = {0, 0, 0, 0};
      ka = __builtin_amdgcn_mfma_f32_16x16x32_f16(ah0, w4h[0], ka, 0, 0, 0);
      kb = __builtin_amdgcn_mfma_f32_16x16x32_f16(al0, w4h[0], kb, 0, 0, 0);
      ua = __builtin_amdgcn_mfma_f32_16x16x32_f16(ah0, mfh[0], ua, 0, 0, 0);
      ub = __builtin_amdgcn_mfma_f32_16x16x32_f16(al0, mfh[0], ub, 0, 0, 0);
      ka = __builtin_amdgcn_mfma_f32_16x16x32_f16(ah1, w4h[1], ka, 0, 0, 0);
      kb = __builtin_amdgcn_mfma_f32_16x16x32_f16(al1, w4h[1], kb, 0, 0, 0);
      ua = __builtin_amdgcn_mfma_f32_16x16x32_f16(ah1, mfh[1], ua, 0, 0, 0);
      ub = __builtin_amdgcn_mfma_f32_16x16x32_f16(al1, mfh[1], ub, 0, 0, 0);
      kOut = ka + kb;
      uOut = ua + ub;
    }
  };

  // k1 = f(y0); FSAL thereafter
  stageA(p_y);
  barrier_lgkm();
  evalR(loadA0(), kk[0], uu[0]);

  // control state in registers (replicated bit-identically across lanes/waves)
  f32x4 tcur = {t0v, t0v, t0v, t0v};
  f32x4 hcur = {0.1f, 0.1f, 0.1f, 0.1f};
  f32x4 hcs, tOldr;
  bool dnr[4];
  bool alldone;

  auto head = [&]() {
    bool all4 = true;
    #pragma unroll
    for (int r = 0; r < 4; ++r) {
      bool d = tcur[r] >= t1v - 1e-6f;
      dnr[r] = d;
      all4 &= d;
      hcs[r] = d ? 0.0f : fminf(hcur[r], t1v - tcur[r]);
      tOldr[r] = tcur[r];
    }
    alldone = (__ballot(all4) == ~0ull);
  };

  // prologue: head for step 0 + stage A of its k2-eval + early L2 frag load
  head();
  if (!alldone) {
    f32x4 p1;
    #pragma unroll
    for (int r = 0; r < 4; ++r) p1[r] = fmaf(hcs[r], A21 * uu[0][r], p_y[r]);
    stageA(p1);
  }
  barrier_lgkm();
  FragsA fNext = loadA0();

  for (int step = 0; step < kMaxSteps && !alldone; ++step) {
    // precondition: h0/l0 for this step's k2-eval published + frags preloaded
    f32x4 p1;
    evalR(fNext, kk[1], uu[1]);

    #pragma unroll
    for (int r = 0; r < 4; ++r)
      p1[r] = fmaf(hcs[r], fmaf(A32, uu[1][r], A31 * uu[0][r]), p_y[r]);
    stageA(p1); barrier_lgkm(); evalR(loadA0(), kk[2], uu[2]);

    #pragma unroll
    for (int r = 0; r < 4; ++r)
      p1[r] = fmaf(hcs[r], fmaf(A43, uu[2][r], fmaf(A42, uu[1][r], A41 * uu[0][r])), p_y[r]);
    stageA(p1); barrier_lgkm(); evalR(loadA0(), kk[3], uu[3]);

    #pragma unroll
    for (int r = 0; r < 4; ++r)
      p1[r] = fmaf(hcs[r], fmaf(A54, uu[3][r], fmaf(A53, uu[2][r],
                  fmaf(A52, uu[1][r], A51 * uu[0][r]))), p_y[r]);
    stageA(p1); barrier_lgkm(); evalR(loadA0(), kk[4], uu[4]);

    #pragma unroll
    for (int r = 0; r < 4; ++r)
      p1[r] = fmaf(hcs[r], fmaf(A65, uu[4][r], fmaf(A64, uu[3][r], fmaf(A63, uu[2][r],
                  fmaf(A62, uu[1][r], A61 * uu[0][r])))), p_y[r]);
    stageA(p1); barrier_lgkm(); evalR(loadA0(), kk[5], uu[5]);

    f32x4 bu;
    #pragma unroll
    for (int r = 0; r < 4; ++r) {
      bu[r] = fmaf(B6, uu[5][r], fmaf(B5, uu[4][r], fmaf(B4, uu[3][r],
              fmaf(B3, uu[2][r], fmaf(B2, uu[1][r], B1 * uu[0][r])))));
      synr[r] = fmaf(hcs[r], fmaf(B6, kk[5][r], fmaf(B5, kk[4][r], fmaf(B4, kk[3][r],
                 fmaf(B3, kk[2][r], fmaf(B2, kk[1][r], B1 * kk[0][r]))))), syr[r]);
      p1[r] = fmaf(hcs[r], bu[r], p_y[r]);
    }
    // early-stash: interp state known pre-k7; drains behind evalR's barriers
    if (w0 && cact) {
      #pragma unroll
      for (int r = 0; r < 4; ++r) {
        int o = (row0 + r) * SD + col;
        sY[o] = syr[r];
        sYN[o] = synr[r];
        sK1[o] = kk[0][r];
      }
    }
    stageA(p1); barrier_lgkm(); evalR(loadA0(), kk[6], uu[6]);   // k7 (FSAL)

    // ---- error norm: per-lane rr^2, 4 xor-shuffle rounds over the 16-group ----
    f32x4 rr2;
    #pragma unroll
    for (int r = 0; r < 4; ++r) {
      float err = hcs[r] * fmaf(E7, kk[6][r], fmaf(E6, kk[5][r], fmaf(E5, kk[4][r],
                  fmaf(E4, kk[3][r], fmaf(E3, kk[2][r], fmaf(E2, kk[1][r], E1 * kk[0][r]))))));
      float sc = fmaf(1e-3f, fmaxf(fabsf(syr[r]), fabsf(synr[r])), 1e-6f);
      float rr = err / sc;
      rr2[r] = cact ? rr * rr : 0.0f;
    }
    #pragma unroll
    for (int m = 1; m < 16; m <<= 1) {
      #pragma unroll
      for (int r = 0; r < 4; ++r) rr2[r] += __shfl_xor(rr2[r], m, 64);
    }

    // ---- controller: work in enorm^2 (sqrt-free; accept test equivalent) ----
    bool okr[4];
    #pragma unroll
    for (int r = 0; r < 4; ++r) {
      float e2 = rr2[r] * 0.2f;                 // enorm^2 = mean over 5 dims
      bool accept = e2 <= 1.0f;                 // == (enorm <= 1)
      float e2c = fmaxf(e2, 1e-20f);            // == max(enorm,1e-10)^2
      float factor = fminf(fmaxf(0.9f * __expf(-0.1f * __logf(e2c)), 0.2f), 10.0f);
      bool ok = accept && !dnr[r];
      okr[r] = ok;
      tcur[r] = ok ? tcur[r] + hcs[r] : tcur[r];
      hcur[r] = dnr[r] ? hcur[r] : hcs[r] * factor;
    }

    // ---- stash k7 + control (current step's tOldr/hcs/tcur) ----
    if (w0 && cact) {
      #pragma unroll
      for (int r = 0; r < 4; ++r) sK7[(row0 + r) * SD + col] = kk[6][r];
    }
    if (w0 && col == 0) {
      #pragma unroll
      for (int r = 0; r < 4; ++r) {
        int m2 = row0 + r;
        ctT[m2] = tOldr[r];
        ctH[m2] = hcs[r];
        ctN[m2] = tcur[r];
        ctO[m2] = okr[r] ? 1.0f : 0.0f;
      }
    }

    // ---- FSAL + state update (registers) ----
    #pragma unroll
    for (int r = 0; r < 4; ++r) {
      if (okr[r]) {
        syr[r] = synr[r];
        kk[0][r] = kk[6][r];
        uu[0][r] = uu[6][r];
        p_y[r] = fmaf(hcs[r], bu[r], p_y[r]);   // p_ynew = W1*ynew + b1 (recursed)
      }
    }

    // ---- next step's head + stage A (pre-barrier), then ONE merged barrier ----
    head();
    if (!alldone) {
      f32x4 pn;
      #pragma unroll
      for (int r = 0; r < 4; ++r) pn[r] = fmaf(hcs[r], A21 * uu[0][r], p_y[r]);
      stageA(pn);   // WAR on h0 safe: last h0 reads were >=2 barriers upstream
    }
    __attribute__((unused)) int dummy = 0;
    barrier_lgkm();   // orders stash + h0 writes; interp fills the b1 shadow

    // early-issue next step's L2 A-frag reads: their ~120cy LDS latency now
    // overlaps the interp block instead of serializing before it
    fNext = loadA0();

    // ---- cubic Hermite interpolation for save points in (t, t_next] ----
    {
      int tt = tid & 15, gg = tid >> 4;
      if (ctO[tt] != 0.0f) {
        float tOld = ctT[tt], hcv = ctH[tt], tNew = ctN[tt];
        float inv = 1.0f / fmaxf(hcv, 1e-12f);
        float yv[kDim], ynv[kDim], k1v[kDim], k7v[kDim];
        #pragma unroll
        for (int d = 0; d < kDim; ++d) {
          yv[d] = sY[tt * SD + d];
          ynv[d] = sYN[tt * SD + d];
          k1v[d] = hcv * sK1[tt * SD + d];
          k7v[d] = hcv * sK7[tt * SD + d];
        }
        #pragma unroll
        for (int q = 0; q < 4; ++q) {
          int n = 4 * gg + q;
          float te = sTe[n];
          if (te > tOld && te <= tNew + 1e-6f) {
            float sx = (te - tOld) * inv;
            float s2 = sx * sx, s3 = s2 * sx;
            float h00 = 2.f * s3 - 3.f * s2 + 1.f;
            float h10 = s3 - 2.f * s2 + sx;
            float h01 = -2.f * s3 + 3.f * s2;
            float h11 = s3 - s2;
            float* op = sOut + n * OS + tt * kDim;   // LDS accumulate, not global
            #pragma unroll
            for (int d = 0; d < kDim; ++d)
              op[d] = h00 * yv[d] + h10 * k1v[d] + h01 * ynv[d] + h11 * k7v[d];
          }
        }
      }
    }
  }

  // ---- flush LDS output accumulator to global, coalesced ----
  barrier_lgkm();
  {
    float* ob = out + (size_t)bid * (kTraj * kSave * kDim);
    for (int idx = tid; idx < kTraj * kSave * kDim; idx += kThreads) {
      int traj = idx / (kSave * kDim);
      int p = idx - traj * (kSave * kDim);
      int n = p / kDim;
      int d = p - n * kDim;
      ob[idx] = sOut[n * OS + traj * kDim + d];
    }
  }
}

}  // namespace

extern "C" void kernel_launch(void* const* d_in, const int* in_sizes, int n_in,
                              void* d_out, int out_size, void* d_ws, size_t ws_size,
                              hipStream_t stream) {
  const float* y0 = (const float*)d_in[0];
  const float* te = (const float*)d_in[1];
  const float* W1 = (const float*)d_in[2];
  const float* b1 = (const float*)d_in[3];
  const float* W2 = (const float*)d_in[4];
  const float* b2 = (const float*)d_in[5];
  const float* W3 = (const float*)d_in[6];
  const float* b3 = (const float*)d_in[7];
  const float* W4 = (const float*)d_in[8];
  const float* b4 = (const float*)d_in[9];
  float* out = (float*)d_out;

  const int batch = in_sizes[0] / kDim;      // 4096
  const int blocks = batch / kTraj;          // 256 blocks x 4 waves = 1 block/CU
  hipLaunchKernelGGL(node_tsit5_kernel, dim3(blocks), dim3(kThreads), 0, stream,
                     y0, te, W1, b1, W2, b2, W3, b3, W4, b4, out);
}

// Round 4
// 105.626 us; speedup vs baseline: 1.0068x; 1.0068x over previous
//
#include <hip/hip_runtime.h>
#include <cmath>

namespace {

constexpr int kDim = 5;
constexpr int kSave = 64;
constexpr int kTraj = 16;      // trajectories per block (= MFMA M)
constexpr int kThreads = 256;  // 4 waves; wave w owns neuron tile [16w,16w+16)
constexpr int kMaxSteps = 64;
constexpr int HS = 72;         // f16 stride: activation planes (144 B)
constexpr int SD = 8;          // f32 stride: small state rows
constexpr int OSS = 8;         // sOut per-(save,traj) slot stride (32 B -> b128+b32)

typedef _Float16 half8 __attribute__((ext_vector_type(8)));
typedef __fp16 fp16x2 __attribute__((ext_vector_type(2)));  // cvt_pkrtz result type
typedef float f32x4 __attribute__((ext_vector_type(4)));

__device__ __forceinline__ float softplusf(float x) {
  return fmaxf(x, 0.0f) + __logf(1.0f + __expf(-fabsf(x)));
}

// lgkm-only workgroup barrier (loop body touches ONLY LDS; no vmcnt drain).
__device__ __forceinline__ void barrier_lgkm() {
  asm volatile("s_waitcnt lgkmcnt(0)" ::: "memory");
  __builtin_amdgcn_s_barrier();
  asm volatile("" ::: "memory");
}

// full-rate cross-lane add via DPP (replaces ds_swizzle shuffles).
// Ctrl must be an ICE -> template parameter.
// 0xB1 = quad_perm(1,0,3,2) = xor1; 0x4E = quad_perm(2,3,0,1) = xor2;
// 0x124 = row_ror:4; 0x128 = row_ror:8.
template <int Ctrl>
__device__ __forceinline__ float dpp_add(float v) {
  int t = __builtin_amdgcn_update_dpp(0, __float_as_int(v), Ctrl, 0xf, 0xf, false);
  return v + __int_as_float(t);
}

struct FragsA { half8 h0a, h1a, l0a, l1a; };

__global__ __launch_bounds__(kThreads, 1)
void node_tsit5_kernel(const float* __restrict__ gy0,
                       const float* __restrict__ gte,
                       const float* __restrict__ gW1, const float* __restrict__ gb1,
                       const float* __restrict__ gW2, const float* __restrict__ gb2,
                       const float* __restrict__ gW3, const float* __restrict__ gb3,
                       const float* __restrict__ gW4, const float* __restrict__ gb4,
                       float* __restrict__ out) {
  const float A21 = 0.161f;
  const float A31 = -0.008480655492356989f, A32 = 0.335480655492357f;
  const float A41 = 2.8971530571054935f, A42 = -6.359448489975075f, A43 = 4.3622954328695815f;
  const float A51 = 5.325864828439257f, A52 = -11.748883564062828f, A53 = 7.4955393428898365f,
              A54 = -0.09249506636175525f;
  const float A61 = 5.86145544294642f, A62 = -12.92096931784711f, A63 = 8.159367898576159f,
              A64 = -0.071584973281401f, A65 = -0.028269050394068383f;
  const float B1 = 0.09646076681806523f, B2 = 0.01f, B3 = 0.4798896504144996f,
              B4 = 1.379008574103742f, B5 = -3.290069515436081f, B6 = 2.324710524099774f;
  const float E1 = -0.00178001105222577714f, E2 = -0.0008164344596567469f,
              E3 = 0.007880878010261995f, E4 = -0.1447110071732629f, E5 = 0.5823571654525552f,
              E6 = -0.45808210592918697f, E7 = 0.015151515151515152f;

  __shared__ __align__(16) _Float16 h0[kTraj * HS], l0[kTraj * HS];
  __shared__ __align__(16) _Float16 h1[kTraj * HS], l1[kTraj * HS];
  __shared__ __align__(16) _Float16 h2[kTraj * HS], l2[kTraj * HS];
  __shared__ float sTe[kSave];
  __shared__ __align__(16) float sY[kTraj * SD], sYN[kTraj * SD];
  __shared__ __align__(16) float sK1[kTraj * SD], sK7[kTraj * SD];
  __shared__ float ctT[kTraj], ctH[kTraj], ctN[kTraj], ctO[kTraj];
  __shared__ __align__(16) float sOut[kSave * kTraj * OSS];  // [save][traj][8], 32 KB

  const int tid = threadIdx.x;
  const int bid = blockIdx.x;
  const int w = tid >> 6;          // wave id = neuron tile
  const int ln = tid & 63;
  const int quad = ln >> 4;
  const int col = ln & 15;
  const int row0 = quad * 4;       // this lane's C-layout trajectories: row0+r
  const int nn = (w << 4) | col;
  const bool cact = col < kDim;    // C-lane carries dim d = col
  const bool w0 = (w == 0);

  // ---- one-time: weight B-frags + biases + fused M = W1*W4 ----
  half8 w2h[2], w3h[2], w4h[2], mfh[2];
  float w1r[kDim];
  #pragma unroll
  for (int d = 0; d < kDim; ++d) w1r[d] = gW1[nn * 5 + d];
  #pragma unroll
  for (int kf = 0; kf < 2; ++kf)
    #pragma unroll
    for (int j = 0; j < 8; ++j) {
      int kk2 = kf * 32 + quad * 8 + j;
      w2h[kf][j] = (_Float16)gW2[nn * 64 + kk2];
      w3h[kf][j] = (_Float16)gW3[nn * 64 + kk2];
      w4h[kf][j] = cact ? (_Float16)gW4[col * 64 + kk2] : (_Float16)0.0f;
      float m = 0.0f;
      #pragma unroll
      for (int d = 0; d < kDim; ++d) m = fmaf(w1r[d], gW4[d * 64 + kk2], m);
      mfh[kf][j] = (_Float16)m;
    }
  const float c1 = gb1[nn], c2 = gb2[nn], c3 = gb3[nn];
  const float c4 = cact ? gb4[col] : 0.0f;   // => k cols>=5 are exactly 0
  float cu = 0.0f;                            // (W1*b4)[nn]
  #pragma unroll
  for (int d = 0; d < kDim; ++d) cu = fmaf(w1r[d], gb4[d], cu);

  // ---- init LDS ----
  if (tid < kSave) sTe[tid] = gte[tid];
  if (tid < kTraj * kDim) {   // sY for the y0 output fill
    int t = tid & 15, d = tid >> 4;
    sY[t * SD + d] = gy0[(size_t)(bid * kTraj + t) * kDim + d];
  }
  {  // zero the LDS output accumulator
    f32x4 zz = {0.f, 0.f, 0.f, 0.f};
    f32x4* z4 = (f32x4*)sOut;
    for (int i = tid; i < (kSave * kTraj * OSS) / 4; i += kThreads) z4[i] = zz;
  }

  // y-state (replicated across waves) + p_y = W1*y + b1 (per wave tile, f32)
  f32x4 syr = {0, 0, 0, 0}, synr = {0, 0, 0, 0}, kk[7], uu[7], p_y;
  #pragma unroll
  for (int r = 0; r < 4; ++r) {
    const float* yr = gy0 + (size_t)(bid * kTraj + row0 + r) * kDim;
    float acc = c1;
    #pragma unroll
    for (int d = 0; d < kDim; ++d) acc = fmaf(w1r[d], yr[d], acc);
    p_y[r] = acc;
    if (cact) syr[r] = yr[col];
  }
  barrier_lgkm();

  const float t0v = sTe[0];
  const float t1v = sTe[kSave - 1];

  // saves at/before t0 get y0 (same-lane overwrite later -> program order)
  {
    int tt = tid & 15, gg = tid >> 4;
    const int sb = tt * SD;
    f32x4 yv4 = *(const f32x4*)(sY + sb);
    float yv4e = sY[sb + 4];
    #pragma unroll
    for (int q = 0; q < 4; ++q) {
      int n = 4 * gg + q;
      if (sTe[n] <= t0v + 1e-6f) {
        float* op = sOut + (n * kTraj + tt) * OSS;
        *(f32x4*)op = yv4;
        op[4] = yv4e;
      }
    }
  }

  // ---- packed softplus epilogue: softplus(a) -> hp/lp planes (4 rows) ----
  auto sp4 = [&](const f32x4& a, _Float16* hp, _Float16* lp) {
    float s0 = softplusf(a[0]), s1 = softplusf(a[1]);
    float s2 = softplusf(a[2]), s3 = softplusf(a[3]);
    fp16x2 hA = __builtin_amdgcn_cvt_pkrtz(s0, s1);
    fp16x2 hB = __builtin_amdgcn_cvt_pkrtz(s2, s3);
    fp16x2 lA = __builtin_amdgcn_cvt_pkrtz(s0 - (float)hA[0], s1 - (float)hA[1]);
    fp16x2 lB = __builtin_amdgcn_cvt_pkrtz(s2 - (float)hB[0], s3 - (float)hB[1]);
    hp[(row0 + 0) * HS + nn] = (_Float16)hA[0]; lp[(row0 + 0) * HS + nn] = (_Float16)lA[0];
    hp[(row0 + 1) * HS + nn] = (_Float16)hA[1]; lp[(row0 + 1) * HS + nn] = (_Float16)lA[1];
    hp[(row0 + 2) * HS + nn] = (_Float16)hB[0]; lp[(row0 + 2) * HS + nn] = (_Float16)lB[0];
    hp[(row0 + 3) * HS + nn] = (_Float16)hB[1]; lp[(row0 + 3) * HS + nn] = (_Float16)lB[1];
  };

  // ---- stage A: softplus(pre1) -> h0/l0 (no barrier; caller barriers) ----
  auto stageA = [&](const f32x4& pre1) { sp4(pre1, h0, l0); };

  // ---- L2 A-fragment load (issue ASAP after the barrier that publishes h0) --
  auto loadA0 = [&]() {
    FragsA f;
    f.h0a = *(const half8*)(h0 + col * HS + quad * 8);
    f.h1a = *(const half8*)(h0 + col * HS + 32 + quad * 8);
    f.l0a = *(const half8*)(l0 + col * HS + quad * 8);
    f.l1a = *(const half8*)(l0 + col * HS + 32 + quad * 8);
    return f;
  };

  // ---- evalR: [L2 | b2 | L3 | b3 | final]; takes preloaded L2 A-frags ----
  auto evalR = [&](FragsA f, f32x4& kOut, f32x4& uOut) {
    {  // L2: f (from h0/l0) -> h1/l1
      f32x4 a = {c2, c2, c2, c2};
      f32x4 b = {0, 0, 0, 0};
      a = __builtin_amdgcn_mfma_f32_16x16x32_f16(f.h0a, w2h[0], a, 0, 0, 0);
      b = __builtin_amdgcn_mfma_f32_16x16x32_f16(f.l0a, w2h[0], b, 0, 0, 0);
      a = __builtin_amdgcn_mfma_f32_16x16x32_f16(f.h1a, w2h[1], a, 0, 0, 0);
      b = __builtin_amdgcn_mfma_f32_16x16x32_f16(f.l1a, w2h[1], b, 0, 0, 0);
      a += b;
      sp4(a, h1, l1);
    }
    barrier_lgkm();   // b2
    {  // L3: h1/l1 -> h2/l2
      half8 ah0 = *(const half8*)(h1 + col * HS + quad * 8);
      half8 ah1 = *(const half8*)(h1 + col * HS + 32 + quad * 8);
      half8 al0 = *(const half8*)(l1 + col * HS + quad * 8);
      half8 al1 = *(const half8*)(l1 + col * HS + 32 + quad * 8);
      f32x4 a = {c3, c3, c3, c3};
      f32x4 b = {0, 0, 0, 0};
      a = __builtin_amdgcn_mfma_f32_16x16x32_f16(ah0, w3h[0], a, 0, 0, 0);
      b = __builtin_amdgcn_mfma_f32_16x16x32_f16(al0, w3h[0], b, 0, 0, 0);
      a = __builtin_amdgcn_mfma_f32_16x16x32_f16(ah1, w3h[1], a, 0, 0, 0);
      b = __builtin_amdgcn_mfma_f32_16x16x32_f16(al1, w3h[1], b, 0, 0, 0);
      a += b;
      sp4(a, h2, l2);
    }
    barrier_lgkm();   // b3
    {  // final: k = W4*h3 + b4 (cols<5) and u = M*h3 + W1*b4 (this tile)
      half8 ah0 = *(const half8*)(h2 + col * HS + quad * 8);
      half8 ah1 = *(const half8*)(h2 + col * HS + 32 + quad * 8);
      half8 al0 = *(const half8*)(l2 + col * HS + quad * 8);
      half8 al1 = *(const half8*)(l2 + col * HS + 32 + quad * 8);
      f32x4 ka = {c4, c4, c4, c4};
      f32x4 kb = {0, 0, 0, 0};
      f32x4 ua = {cu, cu, cu, cu};
      f32x4 ub = {0, 0, 0, 0};
      ka = __builtin_amdgcn_mfma_f32_16x16x32_f16(ah0, w4h[0], ka, 0, 0, 0);
      kb = __builtin_amdgcn_mfma_f32_16x16x32_f16(al0, w4h[0], kb, 0, 0, 0);
      ua = __builtin_amdgcn_mfma_f32_16x16x32_f16(ah0, mfh[0], ua, 0, 0, 0);
      ub = __builtin_amdgcn_mfma_f32_16x16x32_f16(al0, mfh[0], ub, 0, 0, 0);
      ka = __builtin_amdgcn_mfma_f32_16x16x32_f16(ah1, w4h[1], ka, 0, 0, 0);
      kb = __builtin_amdgcn_mfma_f32_16x16x32_f16(al1, w4h[1], kb, 0, 0, 0);
      ua = __builtin_amdgcn_mfma_f32_16x16x32_f16(ah1, mfh[1], ua, 0, 0, 0);
      ub = __builtin_amdgcn_mfma_f32_16x16x32_f16(al1, mfh[1], ub, 0, 0, 0);
      kOut = ka + kb;
      uOut = ua + ub;
    }
  };

  // k1 = f(y0); FSAL thereafter
  stageA(p_y);
  barrier_lgkm();
  evalR(loadA0(), kk[0], uu[0]);

  // control state in registers (replicated bit-identically across lanes/waves)
  f32x4 tcur = {t0v, t0v, t0v, t0v};
  f32x4 hcur = {0.1f, 0.1f, 0.1f, 0.1f};
  f32x4 hcs, tOldr;
  bool dnr[4];
  bool alldone;

  auto head = [&]() {
    bool all4 = true;
    #pragma unroll
    for (int r = 0; r < 4; ++r) {
      bool d = tcur[r] >= t1v - 1e-6f;
      dnr[r] = d;
      all4 &= d;
      hcs[r] = d ? 0.0f : fminf(hcur[r], t1v - tcur[r]);
      tOldr[r] = tcur[r];
    }
    alldone = (__ballot(all4) == ~0ull);
  };

  // prologue: head for step 0 + stage A of its k2-eval + early L2 frag load
  head();
  if (!alldone) {
    f32x4 p1;
    #pragma unroll
    for (int r = 0; r < 4; ++r) p1[r] = fmaf(hcs[r], A21 * uu[0][r], p_y[r]);
    stageA(p1);
  }
  barrier_lgkm();
  FragsA fNext = loadA0();

  for (int step = 0; step < kMaxSteps && !alldone; ++step) {
    // precondition: h0/l0 for this step's k2-eval published + frags preloaded
    f32x4 p1;
    evalR(fNext, kk[1], uu[1]);

    #pragma unroll
    for (int r = 0; r < 4; ++r)
      p1[r] = fmaf(hcs[r], fmaf(A32, uu[1][r], A31 * uu[0][r]), p_y[r]);
    stageA(p1); barrier_lgkm(); evalR(loadA0(), kk[2], uu[2]);

    #pragma unroll
    for (int r = 0; r < 4; ++r)
      p1[r] = fmaf(hcs[r], fmaf(A43, uu[2][r], fmaf(A42, uu[1][r], A41 * uu[0][r])), p_y[r]);
    stageA(p1); barrier_lgkm(); evalR(loadA0(), kk[3], uu[3]);

    #pragma unroll
    for (int r = 0; r < 4; ++r)
      p1[r] = fmaf(hcs[r], fmaf(A54, uu[3][r], fmaf(A53, uu[2][r],
                  fmaf(A52, uu[1][r], A51 * uu[0][r]))), p_y[r]);
    stageA(p1); barrier_lgkm(); evalR(loadA0(), kk[4], uu[4]);

    #pragma unroll
    for (int r = 0; r < 4; ++r)
      p1[r] = fmaf(hcs[r], fmaf(A65, uu[4][r], fmaf(A64, uu[3][r], fmaf(A63, uu[2][r],
                  fmaf(A62, uu[1][r], A61 * uu[0][r])))), p_y[r]);
    stageA(p1); barrier_lgkm(); evalR(loadA0(), kk[5], uu[5]);

    f32x4 bu;
    #pragma unroll
    for (int r = 0; r < 4; ++r) {
      bu[r] = fmaf(B6, uu[5][r], fmaf(B5, uu[4][r], fmaf(B4, uu[3][r],
              fmaf(B3, uu[2][r], fmaf(B2, uu[1][r], B1 * uu[0][r])))));
      synr[r] = fmaf(hcs[r], fmaf(B6, kk[5][r], fmaf(B5, kk[4][r], fmaf(B4, kk[3][r],
                 fmaf(B3, kk[2][r], fmaf(B2, kk[1][r], B1 * kk[0][r]))))), syr[r]);
      p1[r] = fmaf(hcs[r], bu[r], p_y[r]);
    }
    // pre-k7 hoist: E1..E6 error partial + scale (bit-identical fma tree)
    f32x4 epart, scv;
    #pragma unroll
    for (int r = 0; r < 4; ++r) {
      epart[r] = fmaf(E6, kk[5][r], fmaf(E5, kk[4][r], fmaf(E4, kk[3][r],
                 fmaf(E3, kk[2][r], fmaf(E2, kk[1][r], E1 * kk[0][r])))));
      scv[r] = fmaf(1e-3f, fmaxf(fabsf(syr[r]), fabsf(synr[r])), 1e-6f);
    }
    // early-stash: interp state known pre-k7; drains behind evalR's barriers
    if (w0 && cact) {
      #pragma unroll
      for (int r = 0; r < 4; ++r) {
        int o = (row0 + r) * SD + col;
        sY[o] = syr[r];
        sYN[o] = synr[r];
        sK1[o] = kk[0][r];
      }
    }
    stageA(p1); barrier_lgkm(); evalR(loadA0(), kk[6], uu[6]);   // k7 (FSAL)

    // ---- error norm: per-lane rr^2, DPP butterfly over the 16-group ----
    // cols 5..15 are exactly 0 (cact mask), so quad-sums live in quads 0,1 and
    // the ror:4/ror:8 rounds produce the bit-identical total in ALL 16 lanes.
    f32x4 rr2;
    #pragma unroll
    for (int r = 0; r < 4; ++r) {
      float err = hcs[r] * fmaf(E7, kk[6][r], epart[r]);
      float rr = err / scv[r];
      rr2[r] = cact ? rr * rr : 0.0f;
    }
    #pragma unroll
    for (int r = 0; r < 4; ++r) {
      float v = rr2[r];
      v = dpp_add<0xB1>(v);    // xor1 (quad_perm 1,0,3,2)
      v = dpp_add<0x4E>(v);    // xor2 (quad_perm 2,3,0,1)
      v = dpp_add<0x124>(v);   // row_ror:4
      v = dpp_add<0x128>(v);   // row_ror:8
      rr2[r] = v;
    }

    // ---- controller: work in enorm^2 (sqrt-free; accept test equivalent) ----
    bool okr[4];
    #pragma unroll
    for (int r = 0; r < 4; ++r) {
      float e2 = rr2[r] * 0.2f;                 // enorm^2 = mean over 5 dims
      bool accept = e2 <= 1.0f;                 // == (enorm <= 1)
      float e2c = fmaxf(e2, 1e-20f);            // == max(enorm,1e-10)^2
      float factor = fminf(fmaxf(0.9f * __expf(-0.1f * __logf(e2c)), 0.2f), 10.0f);
      bool ok = accept && !dnr[r];
      okr[r] = ok;
      tcur[r] = ok ? tcur[r] + hcs[r] : tcur[r];
      hcur[r] = dnr[r] ? hcur[r] : hcs[r] * factor;
    }

    // ---- stash k7 + control (current step's tOldr/hcs/tcur) ----
    if (w0 && cact) {
      #pragma unroll
      for (int r = 0; r < 4; ++r) sK7[(row0 + r) * SD + col] = kk[6][r];
    }
    if (w0 && col == 0) {
      #pragma unroll
      for (int r = 0; r < 4; ++r) {
        int m2 = row0 + r;
        ctT[m2] = tOldr[r];
        ctH[m2] = hcs[r];
        ctN[m2] = tcur[r];
        ctO[m2] = okr[r] ? 1.0f : 0.0f;
      }
    }

    // ---- FSAL + state update (registers) ----
    #pragma unroll
    for (int r = 0; r < 4; ++r) {
      if (okr[r]) {
        syr[r] = synr[r];
        kk[0][r] = kk[6][r];
        uu[0][r] = uu[6][r];
        p_y[r] = fmaf(hcs[r], bu[r], p_y[r]);   // p_ynew = W1*ynew + b1 (recursed)
      }
    }

    // ---- next step's head + stage A (pre-barrier), then ONE merged barrier ----
    head();
    if (!alldone) {
      f32x4 pn;
      #pragma unroll
      for (int r = 0; r < 4; ++r) pn[r] = fmaf(hcs[r], A21 * uu[0][r], p_y[r]);
      stageA(pn);   // WAR on h0 safe: last h0 reads were >=2 barriers upstream
    }
    barrier_lgkm();   // orders stash + h0 writes; interp fills the b1 shadow

    // early-issue next step's L2 A-frag reads: their LDS latency overlaps interp
    fNext = loadA0();

    // ---- cubic Hermite interpolation for save points in (t, t_next] ----
    {
      int tt = tid & 15, gg = tid >> 4;
      if (ctO[tt] != 0.0f) {
        float tOld = ctT[tt], hcv = ctH[tt], tNew = ctN[tt];
        float inv = 1.0f / fmaxf(hcv, 1e-12f);
        const int sb = tt * SD;
        f32x4 y4  = *(const f32x4*)(sY  + sb); float y4e  = sY [sb + 4];
        f32x4 yn4 = *(const f32x4*)(sYN + sb); float yn4e = sYN[sb + 4];
        f32x4 k14 = *(const f32x4*)(sK1 + sb); float k14e = sK1[sb + 4];
        f32x4 k74 = *(const f32x4*)(sK7 + sb); float k74e = sK7[sb + 4];
        k14 *= hcv; k14e *= hcv;
        k74 *= hcv; k74e *= hcv;
        #pragma unroll
        for (int q = 0; q < 4; ++q) {
          int n = 4 * gg + q;
          float te = sTe[n];
          if (te > tOld && te <= tNew + 1e-6f) {
            float sx = (te - tOld) * inv;
            float s2 = sx * sx, s3 = s2 * sx;
            float h00 = 2.f * s3 - 3.f * s2 + 1.f;
            float h10 = s3 - 2.f * s2 + sx;
            float h01 = -2.f * s3 + 3.f * s2;
            float h11 = s3 - s2;
            f32x4 o = h00 * y4 + h10 * k14 + h01 * yn4 + h11 * k74;
            float oe = h00 * y4e + h10 * k14e + h01 * yn4e + h11 * k74e;
            float* op = sOut + (n * kTraj + tt) * OSS;
            *(f32x4*)op = o;
            op[4] = oe;
          }
        }
      }
    }
  }

  // ---- flush LDS output accumulator to global, coalesced ----
  barrier_lgkm();
  {
    float* ob = out + (size_t)bid * (kTraj * kSave * kDim);
    for (int idx = tid; idx < kTraj * kSave * kDim; idx += kThreads) {
      int traj = idx / (kSave * kDim);
      int p = idx - traj * (kSave * kDim);
      int n = p / kDim;
      int d = p - n * kDim;
      ob[idx] = sOut[(n * kTraj + traj) * OSS + d];
    }
  }
}

}  // namespace

extern "C" void kernel_launch(void* const* d_in, const int* in_sizes, int n_in,
                              void* d_out, int out_size, void* d_ws, size_t ws_size,
                              hipStream_t stream) {
  const float* y0 = (const float*)d_in[0];
  const float* te = (const float*)d_in[1];
  const float* W1 = (const float*)d_in[2];
  const float* b1 = (const float*)d_in[3];
  const float* W2 = (const float*)d_in[4];
  const float* b2 = (const float*)d_in[5];
  const float* W3 = (const float*)d_in[6];
  const float* b3 = (const float*)d_in[7];
  const float* W4 = (const float*)d_in[8];
  const float* b4 = (const float*)d_in[9];
  float* out = (float*)d_out;

  const int batch = in_sizes[0] / kDim;      // 4096
  const int blocks = batch / kTraj;          // 256 blocks x 4 waves = 1 block/CU
  hipLaunchKernelGGL(node_tsit5_kernel, dim3(blocks), dim3(kThreads), 0, stream,
                     y0, te, W1, b1, W2, b2, W3, b3, W4, b4, out);
}

// Round 5
// 105.314 us; speedup vs baseline: 1.0098x; 1.0030x over previous
//
#include <hip/hip_runtime.h>
#include <cmath>

namespace {

constexpr int kDim = 5;
constexpr int kSave = 64;
constexpr int kTraj = 16;      // trajectories per block (= MFMA M)
constexpr int kThreads = 256;  // 4 waves; wave w owns neuron tile [16w,16w+16)
constexpr int kMaxSteps = 64;
constexpr int HS = 72;         // f16 stride: activation planes (144 B)
constexpr int SD = 8;          // f32 stride: small state rows
constexpr int OSS = 8;         // sOut per-(save,traj) slot stride (32 B -> b128+b32)

typedef _Float16 half8 __attribute__((ext_vector_type(8)));
typedef __fp16 fp16x2 __attribute__((ext_vector_type(2)));  // cvt_pkrtz result type
typedef float f32x4 __attribute__((ext_vector_type(4)));

__device__ __forceinline__ float softplusf(float x) {
  return fmaxf(x, 0.0f) + __logf(1.0f + __expf(-fabsf(x)));
}

// lgkm-only workgroup barrier (loop body touches ONLY LDS; no vmcnt drain).
__device__ __forceinline__ void barrier_lgkm() {
  asm volatile("s_waitcnt lgkmcnt(0)" ::: "memory");
  __builtin_amdgcn_s_barrier();
  asm volatile("" ::: "memory");
}

// full-rate cross-lane add via DPP (replaces ds_swizzle shuffles).
// Ctrl must be an ICE -> template parameter.
// 0xB1 = quad_perm(1,0,3,2) = xor1; 0x4E = quad_perm(2,3,0,1) = xor2;
// 0x124 = row_ror:4; 0x128 = row_ror:8.
template <int Ctrl>
__device__ __forceinline__ float dpp_add(float v) {
  int t = __builtin_amdgcn_update_dpp(0, __float_as_int(v), Ctrl, 0xf, 0xf, false);
  return v + __int_as_float(t);
}

struct FragsA { half8 h0a, h1a, l0a, l1a; };

__global__ __launch_bounds__(kThreads, 1)
void node_tsit5_kernel(const float* __restrict__ gy0,
                       const float* __restrict__ gte,
                       const float* __restrict__ gW1, const float* __restrict__ gb1,
                       const float* __restrict__ gW2, const float* __restrict__ gb2,
                       const float* __restrict__ gW3, const float* __restrict__ gb3,
                       const float* __restrict__ gW4, const float* __restrict__ gb4,
                       float* __restrict__ out) {
  const float A21 = 0.161f;
  const float A31 = -0.008480655492356989f, A32 = 0.335480655492357f;
  const float A41 = 2.8971530571054935f, A42 = -6.359448489975075f, A43 = 4.3622954328695815f;
  const float A51 = 5.325864828439257f, A52 = -11.748883564062828f, A53 = 7.4955393428898365f,
              A54 = -0.09249506636175525f;
  const float A61 = 5.86145544294642f, A62 = -12.92096931784711f, A63 = 8.159367898576159f,
              A64 = -0.071584973281401f, A65 = -0.028269050394068383f;
  const float B1 = 0.09646076681806523f, B2 = 0.01f, B3 = 0.4798896504144996f,
              B4 = 1.379008574103742f, B5 = -3.290069515436081f, B6 = 2.324710524099774f;
  const float E1 = -0.00178001105222577714f, E2 = -0.0008164344596567469f,
              E3 = 0.007880878010261995f, E4 = -0.1447110071732629f, E5 = 0.5823571654525552f,
              E6 = -0.45808210592918697f, E7 = 0.015151515151515152f;

  __shared__ __align__(16) _Float16 h0[kTraj * HS], l0[kTraj * HS];
  __shared__ __align__(16) _Float16 h1[kTraj * HS], l1[kTraj * HS];
  __shared__ __align__(16) _Float16 h2[kTraj * HS], l2[kTraj * HS];
  __shared__ float sTe[kSave];
  __shared__ __align__(16) float sY[kTraj * SD], sYN[kTraj * SD];
  __shared__ __align__(16) float sK1[kTraj * SD], sK7[kTraj * SD];
  __shared__ float ctT[kTraj], ctH[kTraj], ctN[kTraj], ctO[kTraj];
  __shared__ __align__(16) float sOut[kSave * kTraj * OSS];  // [save][traj][8], 32 KB

  const int tid = threadIdx.x;
  const int bid = blockIdx.x;
  const int w = tid >> 6;          // wave id = neuron tile
  const int ln = tid & 63;
  const int quad = ln >> 4;
  const int col = ln & 15;
  const int row0 = quad * 4;       // this lane's C-layout trajectories: row0+r
  const int nn = (w << 4) | col;
  const bool cact = col < kDim;    // C-lane carries dim d = col
  const bool w0 = (w == 0);

  // ---- one-time: weight B-frags + biases + fused M = W1*W4 ----
  half8 w2h[2], w3h[2], w4h[2], mfh[2];
  float w1r[kDim];
  #pragma unroll
  for (int d = 0; d < kDim; ++d) w1r[d] = gW1[nn * 5 + d];
  #pragma unroll
  for (int kf = 0; kf < 2; ++kf)
    #pragma unroll
    for (int j = 0; j < 8; ++j) {
      int kk2 = kf * 32 + quad * 8 + j;
      w2h[kf][j] = (_Float16)gW2[nn * 64 + kk2];
      w3h[kf][j] = (_Float16)gW3[nn * 64 + kk2];
      w4h[kf][j] = cact ? (_Float16)gW4[col * 64 + kk2] : (_Float16)0.0f;
      float m = 0.0f;
      #pragma unroll
      for (int d = 0; d < kDim; ++d) m = fmaf(w1r[d], gW4[d * 64 + kk2], m);
      mfh[kf][j] = (_Float16)m;
    }
  const float c1 = gb1[nn], c2 = gb2[nn], c3 = gb3[nn];
  const float c4 = cact ? gb4[col] : 0.0f;   // => k cols>=5 are exactly 0
  float cu = 0.0f;                            // (W1*b4)[nn]
  #pragma unroll
  for (int d = 0; d < kDim; ++d) cu = fmaf(w1r[d], gb4[d], cu);

  // ---- init LDS ----
  if (tid < kSave) sTe[tid] = gte[tid];
  if (tid < kTraj * kDim) {   // sY for the y0 output fill
    int t = tid & 15, d = tid >> 4;
    sY[t * SD + d] = gy0[(size_t)(bid * kTraj + t) * kDim + d];
  }
  {  // zero the LDS output accumulator
    f32x4 zz = {0.f, 0.f, 0.f, 0.f};
    f32x4* z4 = (f32x4*)sOut;
    for (int i = tid; i < (kSave * kTraj * OSS) / 4; i += kThreads) z4[i] = zz;
  }

  // y-state (replicated across waves) + p_y = W1*y + b1 (per wave tile, f32)
  f32x4 syr = {0, 0, 0, 0}, synr = {0, 0, 0, 0}, kk[7], uu[7], p_y;
  #pragma unroll
  for (int r = 0; r < 4; ++r) {
    const float* yr = gy0 + (size_t)(bid * kTraj + row0 + r) * kDim;
    float acc = c1;
    #pragma unroll
    for (int d = 0; d < kDim; ++d) acc = fmaf(w1r[d], yr[d], acc);
    p_y[r] = acc;
    if (cact) syr[r] = yr[col];
  }
  barrier_lgkm();

  const float t0v = sTe[0];
  const float t1v = sTe[kSave - 1];

  // saves at/before t0 get y0 (same-lane overwrite later -> program order)
  {
    int tt = tid & 15, gg = tid >> 4;
    const int sb = tt * SD;
    f32x4 yv4 = *(const f32x4*)(sY + sb);
    float yv4e = sY[sb + 4];
    #pragma unroll
    for (int q = 0; q < 4; ++q) {
      int n = 4 * gg + q;
      if (sTe[n] <= t0v + 1e-6f) {
        float* op = sOut + (n * kTraj + tt) * OSS;
        *(f32x4*)op = yv4;
        op[4] = yv4e;
      }
    }
  }

  // ---- packed softplus epilogue: softplus(a) -> hp/lp planes (4 rows) ----
  auto sp4 = [&](const f32x4& a, _Float16* hp, _Float16* lp) {
    float s0 = softplusf(a[0]), s1 = softplusf(a[1]);
    float s2 = softplusf(a[2]), s3 = softplusf(a[3]);
    fp16x2 hA = __builtin_amdgcn_cvt_pkrtz(s0, s1);
    fp16x2 hB = __builtin_amdgcn_cvt_pkrtz(s2, s3);
    fp16x2 lA = __builtin_amdgcn_cvt_pkrtz(s0 - (float)hA[0], s1 - (float)hA[1]);
    fp16x2 lB = __builtin_amdgcn_cvt_pkrtz(s2 - (float)hB[0], s3 - (float)hB[1]);
    hp[(row0 + 0) * HS + nn] = (_Float16)hA[0]; lp[(row0 + 0) * HS + nn] = (_Float16)lA[0];
    hp[(row0 + 1) * HS + nn] = (_Float16)hA[1]; lp[(row0 + 1) * HS + nn] = (_Float16)lA[1];
    hp[(row0 + 2) * HS + nn] = (_Float16)hB[0]; lp[(row0 + 2) * HS + nn] = (_Float16)lB[0];
    hp[(row0 + 3) * HS + nn] = (_Float16)hB[1]; lp[(row0 + 3) * HS + nn] = (_Float16)lB[1];
  };

  // ---- stage A: softplus(pre1) -> h0/l0 (no barrier; caller barriers) ----
  auto stageA = [&](const f32x4& pre1) { sp4(pre1, h0, l0); };

  // ---- L2 A-fragment load (issue ASAP after the barrier that publishes h0) --
  auto loadA0 = [&]() {
    FragsA f;
    f.h0a = *(const half8*)(h0 + col * HS + quad * 8);
    f.h1a = *(const half8*)(h0 + col * HS + 32 + quad * 8);
    f.l0a = *(const half8*)(l0 + col * HS + quad * 8);
    f.l1a = *(const half8*)(l0 + col * HS + 32 + quad * 8);
    return f;
  };

  // ---- evalR: [L2 | b2 | L3 | b3 | final]; takes preloaded L2 A-frags ----
  auto evalR = [&](FragsA f, f32x4& kOut, f32x4& uOut) {
    {  // L2: f (from h0/l0) -> h1/l1
      f32x4 a = {c2, c2, c2, c2};
      f32x4 b = {0, 0, 0, 0};
      a = __builtin_amdgcn_mfma_f32_16x16x32_f16(f.h0a, w2h[0], a, 0, 0, 0);
      b = __builtin_amdgcn_mfma_f32_16x16x32_f16(f.l0a, w2h[0], b, 0, 0, 0);
      a = __builtin_amdgcn_mfma_f32_16x16x32_f16(f.h1a, w2h[1], a, 0, 0, 0);
      b = __builtin_amdgcn_mfma_f32_16x16x32_f16(f.l1a, w2h[1], b, 0, 0, 0);
      a += b;
      sp4(a, h1, l1);
    }
    barrier_lgkm();   // b2
    {  // L3: h1/l1 -> h2/l2
      half8 ah0 = *(const half8*)(h1 + col * HS + quad * 8);
      half8 ah1 = *(const half8*)(h1 + col * HS + 32 + quad * 8);
      half8 al0 = *(const half8*)(l1 + col * HS + quad * 8);
      half8 al1 = *(const half8*)(l1 + col * HS + 32 + quad * 8);
      f32x4 a = {c3, c3, c3, c3};
      f32x4 b = {0, 0, 0, 0};
      a = __builtin_amdgcn_mfma_f32_16x16x32_f16(ah0, w3h[0], a, 0, 0, 0);
      b = __builtin_amdgcn_mfma_f32_16x16x32_f16(al0, w3h[0], b, 0, 0, 0);
      a = __builtin_amdgcn_mfma_f32_16x16x32_f16(ah1, w3h[1], a, 0, 0, 0);
      b = __builtin_amdgcn_mfma_f32_16x16x32_f16(al1, w3h[1], b, 0, 0, 0);
      a += b;
      sp4(a, h2, l2);
    }
    barrier_lgkm();   // b3
    {  // final: k = W4*h3 + b4 (cols<5) and u = M*h3 + W1*b4 (this tile)
      half8 ah0 = *(const half8*)(h2 + col * HS + quad * 8);
      half8 ah1 = *(const half8*)(h2 + col * HS + 32 + quad * 8);
      half8 al0 = *(const half8*)(l2 + col * HS + quad * 8);
      half8 al1 = *(const half8*)(l2 + col * HS + 32 + quad * 8);
      f32x4 ka = {c4, c4, c4, c4};
      f32x4 kb = {0, 0, 0, 0};
      f32x4 ua = {cu, cu, cu, cu};
      f32x4 ub = {0, 0, 0, 0};
      ka = __builtin_amdgcn_mfma_f32_16x16x32_f16(ah0, w4h[0], ka, 0, 0, 0);
      kb = __builtin_amdgcn_mfma_f32_16x16x32_f16(al0, w4h[0], kb, 0, 0, 0);
      ua = __builtin_amdgcn_mfma_f32_16x16x32_f16(ah0, mfh[0], ua, 0, 0, 0);
      ub = __builtin_amdgcn_mfma_f32_16x16x32_f16(al0, mfh[0], ub, 0, 0, 0);
      ka = __builtin_amdgcn_mfma_f32_16x16x32_f16(ah1, w4h[1], ka, 0, 0, 0);
      kb = __builtin_amdgcn_mfma_f32_16x16x32_f16(al1, w4h[1], kb, 0, 0, 0);
      ua = __builtin_amdgcn_mfma_f32_16x16x32_f16(ah1, mfh[1], ua, 0, 0, 0);
      ub = __builtin_amdgcn_mfma_f32_16x16x32_f16(al1, mfh[1], ub, 0, 0, 0);
      kOut = ka + kb;
      uOut = ua + ub;
    }
  };

  // k1 = f(y0); FSAL thereafter
  stageA(p_y);
  barrier_lgkm();
  evalR(loadA0(), kk[0], uu[0]);

  // control state in registers (replicated bit-identically across lanes/waves)
  f32x4 tcur = {t0v, t0v, t0v, t0v};
  f32x4 hcur = {0.1f, 0.1f, 0.1f, 0.1f};
  f32x4 hcs, tOldr;
  bool dnr[4];
  bool alldone;

  auto head = [&]() {
    bool all4 = true;
    #pragma unroll
    for (int r = 0; r < 4; ++r) {
      bool d = tcur[r] >= t1v - 1e-6f;
      dnr[r] = d;
      all4 &= d;
      hcs[r] = d ? 0.0f : fminf(hcur[r], t1v - tcur[r]);
      tOldr[r] = tcur[r];
    }
    alldone = (__ballot(all4) == ~0ull);
  };

  // prologue: head for step 0 + stage A of its k2-eval + early L2 frag load
  head();
  if (!alldone) {
    f32x4 p1;
    #pragma unroll
    for (int r = 0; r < 4; ++r) p1[r] = fmaf(hcs[r], A21 * uu[0][r], p_y[r]);
    stageA(p1);
  }
  barrier_lgkm();
  FragsA fNext = loadA0();

  for (int step = 0; step < kMaxSteps && !alldone; ++step) {
    // precondition: h0/l0 for this step's k2-eval published + frags preloaded
    f32x4 p1;
    // Horner-prefix registers: bit-identical prefixes of the round-4 fma trees,
    // computed one eval early so the post-uu[j] chain is 2 fma, not 5.
    f32x4 T4, T5, T6, Tbu, Tbk, Te;
    evalR(fNext, kk[1], uu[1]);

    #pragma unroll
    for (int r = 0; r < 4; ++r) {
      p1[r] = fmaf(hcs[r], fmaf(A32, uu[1][r], A31 * uu[0][r]), p_y[r]);
      T4[r] = fmaf(A42, uu[1][r], A41 * uu[0][r]);
    }
    stageA(p1); barrier_lgkm(); evalR(loadA0(), kk[2], uu[2]);

    #pragma unroll
    for (int r = 0; r < 4; ++r) {
      p1[r] = fmaf(hcs[r], fmaf(A43, uu[2][r], T4[r]), p_y[r]);
      T5[r] = fmaf(A53, uu[2][r], fmaf(A52, uu[1][r], A51 * uu[0][r]));
    }
    stageA(p1); barrier_lgkm(); evalR(loadA0(), kk[3], uu[3]);

    #pragma unroll
    for (int r = 0; r < 4; ++r) {
      p1[r] = fmaf(hcs[r], fmaf(A54, uu[3][r], T5[r]), p_y[r]);
      T6[r] = fmaf(A64, uu[3][r], fmaf(A63, uu[2][r], fmaf(A62, uu[1][r], A61 * uu[0][r])));
    }
    stageA(p1); barrier_lgkm(); evalR(loadA0(), kk[4], uu[4]);

    #pragma unroll
    for (int r = 0; r < 4; ++r) {
      p1[r] = fmaf(hcs[r], fmaf(A65, uu[4][r], T6[r]), p_y[r]);
      Tbu[r] = fmaf(B5, uu[4][r], fmaf(B4, uu[3][r], fmaf(B3, uu[2][r],
               fmaf(B2, uu[1][r], B1 * uu[0][r]))));
      Tbk[r] = fmaf(B5, kk[4][r], fmaf(B4, kk[3][r], fmaf(B3, kk[2][r],
               fmaf(B2, kk[1][r], B1 * kk[0][r]))));
      Te[r]  = fmaf(E5, kk[4][r], fmaf(E4, kk[3][r], fmaf(E3, kk[2][r],
               fmaf(E2, kk[1][r], E1 * kk[0][r]))));
    }
    stageA(p1); barrier_lgkm(); evalR(loadA0(), kk[5], uu[5]);

    f32x4 bu, epart, scv;
    #pragma unroll
    for (int r = 0; r < 4; ++r) {
      bu[r] = fmaf(B6, uu[5][r], Tbu[r]);
      synr[r] = fmaf(hcs[r], fmaf(B6, kk[5][r], Tbk[r]), syr[r]);
      epart[r] = fmaf(E6, kk[5][r], Te[r]);
      scv[r] = fmaf(1e-3f, fmaxf(fabsf(syr[r]), fabsf(synr[r])), 1e-6f);
      p1[r] = fmaf(hcs[r], bu[r], p_y[r]);
    }
    // early-stash: interp state known pre-k7; drains behind evalR's barriers
    if (w0 && cact) {
      #pragma unroll
      for (int r = 0; r < 4; ++r) {
        int o = (row0 + r) * SD + col;
        sY[o] = syr[r];
        sYN[o] = synr[r];
        sK1[o] = kk[0][r];
      }
    }
    stageA(p1); barrier_lgkm(); evalR(loadA0(), kk[6], uu[6]);   // k7 (FSAL)

    // stash k7 immediately: ds_writes drain under the DPP/controller VALU
    if (w0 && cact) {
      #pragma unroll
      for (int r = 0; r < 4; ++r) sK7[(row0 + r) * SD + col] = kk[6][r];
    }

    // ---- error norm: per-lane rr^2, DPP butterfly over the 16-group ----
    // cols 5..15 are exactly 0 (cact mask), so quad-sums live in quads 0,1 and
    // the ror:4/ror:8 rounds produce the bit-identical total in ALL 16 lanes.
    f32x4 rr2;
    #pragma unroll
    for (int r = 0; r < 4; ++r) {
      float err = hcs[r] * fmaf(E7, kk[6][r], epart[r]);
      float rr = err * __builtin_amdgcn_rcpf(scv[r]);   // ~1ulp vs exact divide
      rr2[r] = cact ? rr * rr : 0.0f;
    }
    #pragma unroll
    for (int r = 0; r < 4; ++r) {
      float v = rr2[r];
      v = dpp_add<0xB1>(v);    // xor1 (quad_perm 1,0,3,2)
      v = dpp_add<0x4E>(v);    // xor2 (quad_perm 2,3,0,1)
      v = dpp_add<0x124>(v);   // row_ror:4
      v = dpp_add<0x128>(v);   // row_ror:8
      rr2[r] = v;
    }

    // ---- controller: work in enorm^2 (sqrt-free; accept test equivalent) ----
    bool okr[4];
    #pragma unroll
    for (int r = 0; r < 4; ++r) {
      float e2 = rr2[r] * 0.2f;                 // enorm^2 = mean over 5 dims
      bool accept = e2 <= 1.0f;                 // == (enorm <= 1)
      float e2c = fmaxf(e2, 1e-20f);            // == max(enorm,1e-10)^2
      float factor = fminf(fmaxf(0.9f * __expf(-0.1f * __logf(e2c)), 0.2f), 10.0f);
      bool ok = accept && !dnr[r];
      okr[r] = ok;
      tcur[r] = ok ? tcur[r] + hcs[r] : tcur[r];
      hcur[r] = dnr[r] ? hcur[r] : hcs[r] * factor;
    }

    // ---- stash control (current step's tOldr/hcs/tcur) ----
    if (w0 && col == 0) {
      #pragma unroll
      for (int r = 0; r < 4; ++r) {
        int m2 = row0 + r;
        ctT[m2] = tOldr[r];
        ctH[m2] = hcs[r];
        ctN[m2] = tcur[r];
        ctO[m2] = okr[r] ? 1.0f : 0.0f;
      }
    }

    // ---- FSAL + state update (registers) ----
    #pragma unroll
    for (int r = 0; r < 4; ++r) {
      if (okr[r]) {
        syr[r] = synr[r];
        kk[0][r] = kk[6][r];
        uu[0][r] = uu[6][r];
        p_y[r] = fmaf(hcs[r], bu[r], p_y[r]);   // p_ynew = W1*ynew + b1 (recursed)
      }
    }

    // ---- next step's head + stage A (pre-barrier), then ONE merged barrier ----
    head();
    if (!alldone) {
      f32x4 pn;
      #pragma unroll
      for (int r = 0; r < 4; ++r) pn[r] = fmaf(hcs[r], A21 * uu[0][r], p_y[r]);
      stageA(pn);   // WAR on h0 safe: last h0 reads were >=2 barriers upstream
    }
    barrier_lgkm();   // orders stash + h0 writes; interp fills the b1 shadow

    // early-issue next step's L2 A-frag reads: their LDS latency overlaps interp
    fNext = loadA0();

    // ---- cubic Hermite interpolation for save points in (t, t_next] ----
    {
      int tt = tid & 15, gg = tid >> 4;
      if (ctO[tt] != 0.0f) {
        float tOld = ctT[tt], hcv = ctH[tt], tNew = ctN[tt];
        float inv = __builtin_amdgcn_rcpf(fmaxf(hcv, 1e-12f));
        const int sb = tt * SD;
        f32x4 y4  = *(const f32x4*)(sY  + sb); float y4e  = sY [sb + 4];
        f32x4 yn4 = *(const f32x4*)(sYN + sb); float yn4e = sYN[sb + 4];
        f32x4 k14 = *(const f32x4*)(sK1 + sb); float k14e = sK1[sb + 4];
        f32x4 k74 = *(const f32x4*)(sK7 + sb); float k74e = sK7[sb + 4];
        k14 *= hcv; k14e *= hcv;
        k74 *= hcv; k74e *= hcv;
        #pragma unroll
        for (int q = 0; q < 4; ++q) {
          int n = 4 * gg + q;
          float te = sTe[n];
          if (te > tOld && te <= tNew + 1e-6f) {
            float sx = (te - tOld) * inv;
            float s2 = sx * sx, s3 = s2 * sx;
            float h00 = 2.f * s3 - 3.f * s2 + 1.f;
            float h10 = s3 - 2.f * s2 + sx;
            float h01 = -2.f * s3 + 3.f * s2;
            float h11 = s3 - s2;
            f32x4 o = h00 * y4 + h10 * k14 + h01 * yn4 + h11 * k74;
            float oe = h00 * y4e + h10 * k14e + h01 * yn4e + h11 * k74e;
            float* op = sOut + (n * kTraj + tt) * OSS;
            *(f32x4*)op = o;
            op[4] = oe;
          }
        }
      }
    }
  }

  // ---- flush LDS output accumulator to global, coalesced ----
  barrier_lgkm();
  {
    float* ob = out + (size_t)bid * (kTraj * kSave * kDim);
    for (int idx = tid; idx < kTraj * kSave * kDim; idx += kThreads) {
      int traj = idx / (kSave * kDim);
      int p = idx - traj * (kSave * kDim);
      int n = p / kDim;
      int d = p - n * kDim;
      ob[idx] = sOut[(n * kTraj + traj) * OSS + d];
    }
  }
}

}  // namespace

extern "C" void kernel_launch(void* const* d_in, const int* in_sizes, int n_in,
                              void* d_out, int out_size, void* d_ws, size_t ws_size,
                              hipStream_t stream) {
  const float* y0 = (const float*)d_in[0];
  const float* te = (const float*)d_in[1];
  const float* W1 = (const float*)d_in[2];
  const float* b1 = (const float*)d_in[3];
  const float* W2 = (const float*)d_in[4];
  const float* b2 = (const float*)d_in[5];
  const float* W3 = (const float*)d_in[6];
  const float* b3 = (const float*)d_in[7];
  const float* W4 = (const float*)d_in[8];
  const float* b4 = (const float*)d_in[9];
  float* out = (float*)d_out;

  const int batch = in_sizes[0] / kDim;      // 4096
  const int blocks = batch / kTraj;          // 256 blocks x 4 waves = 1 block/CU
  hipLaunchKernelGGL(node_tsit5_kernel, dim3(blocks), dim3(kThreads), 0, stream,
                     y0, te, W1, b1, W2, b2, W3, b3, W4, b4, out);
}

// Round 7
// 104.538 us; speedup vs baseline: 1.0173x; 1.0074x over previous
//
#include <hip/hip_runtime.h>
#include <cmath>

namespace {

constexpr int kDim = 5;
constexpr int kSave = 64;
constexpr int kTraj = 16;      // trajectories per block (= MFMA M)
constexpr int kThreads = 256;  // 4 waves; wave w owns neuron tile [16w,16w+16)
constexpr int kMaxSteps = 64;
constexpr int HS2 = 136;       // halves per row of interleaved (h,l) plane = 272 B
                               // row stride 68 dw: 16B-aligned, 2-way-bank on writes
constexpr int SD = 8;          // f32 stride: small state rows
constexpr int OSS = 8;         // sOut per-(save,traj) slot stride (32 B -> b128+b32)

typedef _Float16 half8 __attribute__((ext_vector_type(8)));
typedef __fp16 fp16x2 __attribute__((ext_vector_type(2)));  // cvt_pkrtz result type
typedef float f32x4 __attribute__((ext_vector_type(4)));

__device__ __forceinline__ float softplusf(float x) {
  return fmaxf(x, 0.0f) + __logf(1.0f + __expf(-fabsf(x)));
}

// lgkm-only workgroup barrier (loop body touches ONLY LDS; no vmcnt drain).
__device__ __forceinline__ void barrier_lgkm() {
  asm volatile("s_waitcnt lgkmcnt(0)" ::: "memory");
  __builtin_amdgcn_s_barrier();
  asm volatile("" ::: "memory");
}

// full-rate cross-lane add via DPP. Ctrl must be an ICE -> template parameter.
// 0xB1 = quad_perm(1,0,3,2) = xor1; 0x4E = quad_perm(2,3,0,1) = xor2;
// 0x124 = row_ror:4; 0x128 = row_ror:8.
template <int Ctrl>
__device__ __forceinline__ float dpp_add(float v) {
  int t = __builtin_amdgcn_update_dpp(0, __float_as_int(v), Ctrl, 0xf, 0xf, false);
  return v + __int_as_float(t);
}

struct FragsA { half8 a0, a1, a2, a3; };  // virtual-K=128 interleaved (h,l)

__global__ __launch_bounds__(kThreads, 1)
void node_tsit5_kernel(const float* __restrict__ gy0,
                       const float* __restrict__ gte,
                       const float* __restrict__ gW1, const float* __restrict__ gb1,
                       const float* __restrict__ gW2, const float* __restrict__ gb2,
                       const float* __restrict__ gW3, const float* __restrict__ gb3,
                       const float* __restrict__ gW4, const float* __restrict__ gb4,
                       float* __restrict__ out) {
  const float A21 = 0.161f;
  const float A31 = -0.008480655492356989f, A32 = 0.335480655492357f;
  const float A41 = 2.8971530571054935f, A42 = -6.359448489975075f, A43 = 4.3622954328695815f;
  const float A51 = 5.325864828439257f, A52 = -11.748883564062828f, A53 = 7.4955393428898365f,
              A54 = -0.09249506636175525f;
  const float A61 = 5.86145544294642f, A62 = -12.92096931784711f, A63 = 8.159367898576159f,
              A64 = -0.071584973281401f, A65 = -0.028269050394068383f;
  const float B1 = 0.09646076681806523f, B2 = 0.01f, B3 = 0.4798896504144996f,
              B4 = 1.379008574103742f, B5 = -3.290069515436081f, B6 = 2.324710524099774f;
  const float E1 = -0.00178001105222577714f, E2 = -0.0008164344596567469f,
              E3 = 0.007880878010261995f, E4 = -0.1447110071732629f, E5 = 0.5823571654525552f,
              E6 = -0.45808210592918697f, E7 = 0.015151515151515152f;

  // interleaved (h,l) activation planes: row = trajectory, half-index vk = 2*neuron+{0,1}
  __shared__ __align__(16) _Float16 hl0[kTraj * HS2];
  __shared__ __align__(16) _Float16 hl1[kTraj * HS2];
  __shared__ __align__(16) _Float16 hl2[kTraj * HS2];
  __shared__ float sTe[kSave];
  __shared__ __align__(16) float sY[kTraj * SD], sYN[kTraj * SD];
  __shared__ __align__(16) float sK1[kTraj * SD], sK7[kTraj * SD];
  __shared__ float ctT[kTraj], ctH[kTraj], ctN[kTraj], ctO[kTraj];
  __shared__ __align__(16) float sOut[kSave * kTraj * OSS];  // [save][traj][8], 32 KB

  const int tid = threadIdx.x;
  const int bid = blockIdx.x;
  const int w = tid >> 6;          // wave id = neuron tile
  const int ln = tid & 63;
  const int quad = ln >> 4;
  const int col = ln & 15;
  const int row0 = quad * 4;       // this lane's C-layout trajectories: row0+r
  const int nn = (w << 4) | col;
  const bool cact = col < kDim;    // C-lane carries dim d = col
  const bool w0 = (w == 0);

  // ---- one-time: weight B-frags (duplicated per h/l parity) + biases + M = W1*W4 ----
  half8 w2h[4], w3h[4], w4h[4], mfh[4];
  float w1r[kDim];
  #pragma unroll
  for (int d = 0; d < kDim; ++d) w1r[d] = gW1[nn * 5 + d];
  #pragma unroll
  for (int t = 0; t < 4; ++t)
    #pragma unroll
    for (int j = 0; j < 8; ++j) {
      int neuron = (t * 32 + quad * 8 + j) >> 1;   // vk>>1: W duplicated for h and l
      w2h[t][j] = (_Float16)gW2[nn * 64 + neuron];
      w3h[t][j] = (_Float16)gW3[nn * 64 + neuron];
      w4h[t][j] = cact ? (_Float16)gW4[col * 64 + neuron] : (_Float16)0.0f;
      float m = 0.0f;
      #pragma unroll
      for (int d = 0; d < kDim; ++d) m = fmaf(w1r[d], gW4[d * 64 + neuron], m);
      mfh[t][j] = (_Float16)m;
    }
  const float c1 = gb1[nn], c2 = gb2[nn], c3 = gb3[nn];
  const float c4 = cact ? gb4[col] : 0.0f;   // => k cols>=5 are exactly 0
  float cu = 0.0f;                            // (W1*b4)[nn]
  #pragma unroll
  for (int d = 0; d < kDim; ++d) cu = fmaf(w1r[d], gb4[d], cu);

  // ---- init LDS ----
  if (tid < kSave) sTe[tid] = gte[tid];
  if (tid < kTraj * kDim) {   // sY for the y0 output fill
    int t = tid & 15, d = tid >> 4;
    sY[t * SD + d] = gy0[(size_t)(bid * kTraj + t) * kDim + d];
  }
  {  // zero the LDS output accumulator
    f32x4 zz = {0.f, 0.f, 0.f, 0.f};
    f32x4* z4 = (f32x4*)sOut;
    for (int i = tid; i < (kSave * kTraj * OSS) / 4; i += kThreads) z4[i] = zz;
  }

  // y-state (replicated across waves) + p_y = W1*y + b1 (per wave tile, f32)
  f32x4 syr = {0, 0, 0, 0}, synr = {0, 0, 0, 0}, kk[7], uu[7], p_y;
  #pragma unroll
  for (int r = 0; r < 4; ++r) {
    const float* yr = gy0 + (size_t)(bid * kTraj + row0 + r) * kDim;
    float acc = c1;
    #pragma unroll
    for (int d = 0; d < kDim; ++d) acc = fmaf(w1r[d], yr[d], acc);
    p_y[r] = acc;
    if (cact) syr[r] = yr[col];
  }
  barrier_lgkm();

  const float t0v = sTe[0];
  const float t1v = sTe[kSave - 1];

  // per-lane save-times: loop-invariant -> registers (kills 4 ds_reads/step in interp)
  const int ggl = tid >> 4;
  float teq[4];
  #pragma unroll
  for (int q = 0; q < 4; ++q) teq[q] = sTe[4 * ggl + q];

  // saves at/before t0 get y0 (same-lane overwrite later -> program order)
  {
    int tt = tid & 15;
    const int sb = tt * SD;
    f32x4 yv4 = *(const f32x4*)(sY + sb);
    float yv4e = sY[sb + 4];
    #pragma unroll
    for (int q = 0; q < 4; ++q) {
      int n = 4 * ggl + q;
      if (teq[q] <= t0v + 1e-6f) {
        float* op = sOut + (n * kTraj + tt) * OSS;
        *(f32x4*)op = yv4;
        op[4] = yv4e;
      }
    }
  }

  // ---- packed softplus epilogue: softplus(a) -> interleaved (h,l) plane, 4 rows ----
  // h = RTZ-f16(s); l = RTZ-f16(s - (float)h); one b32 store per row (2-way banks).
  auto sp4 = [&](const f32x4& a, _Float16* hl) {
    #pragma unroll
    for (int r = 0; r < 4; ++r) {
      float s = softplusf(a[r]);
      fp16x2 t0 = __builtin_amdgcn_cvt_pkrtz(s, s);
      float hf = (float)t0[0];
      fp16x2 p = __builtin_amdgcn_cvt_pkrtz(s, s - hf);   // (h, l)
      *(fp16x2*)(hl + (row0 + r) * HS2 + nn * 2) = p;
    }
  };

  // ---- stage A: softplus(pre1) -> hl0 (no barrier; caller barriers) ----
  auto stageA = [&](const f32x4& pre1) { sp4(pre1, hl0); };

  // ---- A-fragment load: 4x b128, virtual K=128 over interleaved (h,l) ----
  auto loadF = [&](const _Float16* hl) {
    FragsA f;
    const _Float16* base = hl + col * HS2 + quad * 8;
    f.a0 = *(const half8*)(base);
    f.a1 = *(const half8*)(base + 32);
    f.a2 = *(const half8*)(base + 64);
    f.a3 = *(const half8*)(base + 96);
    return f;
  };
  auto loadA0 = [&]() { return loadF(hl0); };

  // ---- evalR: [L2 | b2 | L3 | b3 | final]; takes preloaded L2 A-frags ----
  auto evalR = [&](FragsA f, f32x4& kOut, f32x4& uOut) {
    {  // L2: hl0 -> hl1 (two ILP chains, h+l fused in-K)
      f32x4 a = {c2, c2, c2, c2};
      f32x4 b = {0, 0, 0, 0};
      a = __builtin_amdgcn_mfma_f32_16x16x32_f16(f.a0, w2h[0], a, 0, 0, 0);
      b = __builtin_amdgcn_mfma_f32_16x16x32_f16(f.a1, w2h[1], b, 0, 0, 0);
      a = __builtin_amdgcn_mfma_f32_16x16x32_f16(f.a2, w2h[2], a, 0, 0, 0);
      b = __builtin_amdgcn_mfma_f32_16x16x32_f16(f.a3, w2h[3], b, 0, 0, 0);
      a += b;
      sp4(a, hl1);
    }
    barrier_lgkm();   // b2
    {  // L3: hl1 -> hl2
      FragsA g = loadF(hl1);
      f32x4 a = {c3, c3, c3, c3};
      f32x4 b = {0, 0, 0, 0};
      a = __builtin_amdgcn_mfma_f32_16x16x32_f16(g.a0, w3h[0], a, 0, 0, 0);
      b = __builtin_amdgcn_mfma_f32_16x16x32_f16(g.a1, w3h[1], b, 0, 0, 0);
      a = __builtin_amdgcn_mfma_f32_16x16x32_f16(g.a2, w3h[2], a, 0, 0, 0);
      b = __builtin_amdgcn_mfma_f32_16x16x32_f16(g.a3, w3h[3], b, 0, 0, 0);
      a += b;
      sp4(a, hl2);
    }
    barrier_lgkm();   // b3
    {  // final: k = W4*h3 + b4 (cols<5) and u = M*h3 + W1*b4 (this tile)
      FragsA g = loadF(hl2);
      f32x4 ka = {c4, c4, c4, c4};
      f32x4 kb = {0, 0, 0, 0};
      f32x4 ua = {cu, cu, cu, cu};
      f32x4 ub = {0, 0, 0, 0};
      ka = __builtin_amdgcn_mfma_f32_16x16x32_f16(g.a0, w4h[0], ka, 0, 0, 0);
      kb = __builtin_amdgcn_mfma_f32_16x16x32_f16(g.a1, w4h[1], kb, 0, 0, 0);
      ua = __builtin_amdgcn_mfma_f32_16x16x32_f16(g.a0, mfh[0], ua, 0, 0, 0);
      ub = __builtin_amdgcn_mfma_f32_16x16x32_f16(g.a1, mfh[1], ub, 0, 0, 0);
      ka = __builtin_amdgcn_mfma_f32_16x16x32_f16(g.a2, w4h[2], ka, 0, 0, 0);
      kb = __builtin_amdgcn_mfma_f32_16x16x32_f16(g.a3, w4h[3], kb, 0, 0, 0);
      ua = __builtin_amdgcn_mfma_f32_16x16x32_f16(g.a2, mfh[2], ua, 0, 0, 0);
      ub = __builtin_amdgcn_mfma_f32_16x16x32_f16(g.a3, mfh[3], ub, 0, 0, 0);
      kOut = ka + kb;
      uOut = ua + ub;
    }
  };

  // k1 = f(y0); FSAL thereafter
  stageA(p_y);
  barrier_lgkm();
  evalR(loadA0(), kk[0], uu[0]);

  // control state in registers (replicated bit-identically across lanes/waves)
  f32x4 tcur = {t0v, t0v, t0v, t0v};
  f32x4 hcur = {0.1f, 0.1f, 0.1f, 0.1f};
  f32x4 hcs, tOldr;
  bool dnr[4];
  bool alldone;

  auto head = [&]() {
    bool all4 = true;
    #pragma unroll
    for (int r = 0; r < 4; ++r) {
      bool d = tcur[r] >= t1v - 1e-6f;
      dnr[r] = d;
      all4 &= d;
      hcs[r] = d ? 0.0f : fminf(hcur[r], t1v - tcur[r]);
      tOldr[r] = tcur[r];
    }
    alldone = (__ballot(all4) == ~0ull);
  };

  // prologue: head for step 0 + stage A of its k2-eval + early L2 frag load
  head();
  if (!alldone) {
    f32x4 p1;
    #pragma unroll
    for (int r = 0; r < 4; ++r) p1[r] = fmaf(hcs[r], A21 * uu[0][r], p_y[r]);
    stageA(p1);
  }
  barrier_lgkm();
  FragsA fNext = loadA0();

  for (int step = 0; step < kMaxSteps && !alldone; ++step) {
    // precondition: hl0 for this step's k2-eval published + frags preloaded
    f32x4 p1;
    // Horner-prefix registers: bit-identical prefixes of the fma trees,
    // computed one eval early so the post-uu[j] chain is 2 fma, not 5.
    f32x4 T4, T5, T6, Tbu, Tbk, Te;
    evalR(fNext, kk[1], uu[1]);

    #pragma unroll
    for (int r = 0; r < 4; ++r) {
      p1[r] = fmaf(hcs[r], fmaf(A32, uu[1][r], A31 * uu[0][r]), p_y[r]);
      T4[r] = fmaf(A42, uu[1][r], A41 * uu[0][r]);
    }
    stageA(p1); barrier_lgkm(); evalR(loadA0(), kk[2], uu[2]);

    #pragma unroll
    for (int r = 0; r < 4; ++r) {
      p1[r] = fmaf(hcs[r], fmaf(A43, uu[2][r], T4[r]), p_y[r]);
      T5[r] = fmaf(A53, uu[2][r], fmaf(A52, uu[1][r], A51 * uu[0][r]));
    }
    stageA(p1); barrier_lgkm(); evalR(loadA0(), kk[3], uu[3]);

    #pragma unroll
    for (int r = 0; r < 4; ++r) {
      p1[r] = fmaf(hcs[r], fmaf(A54, uu[3][r], T5[r]), p_y[r]);
      T6[r] = fmaf(A64, uu[3][r], fmaf(A63, uu[2][r], fmaf(A62, uu[1][r], A61 * uu[0][r])));
    }
    stageA(p1); barrier_lgkm(); evalR(loadA0(), kk[4], uu[4]);

    #pragma unroll
    for (int r = 0; r < 4; ++r) {
      p1[r] = fmaf(hcs[r], fmaf(A65, uu[4][r], T6[r]), p_y[r]);
      Tbu[r] = fmaf(B5, uu[4][r], fmaf(B4, uu[3][r], fmaf(B3, uu[2][r],
               fmaf(B2, uu[1][r], B1 * uu[0][r]))));
      Tbk[r] = fmaf(B5, kk[4][r], fmaf(B4, kk[3][r], fmaf(B3, kk[2][r],
               fmaf(B2, kk[1][r], B1 * kk[0][r]))));
      Te[r]  = fmaf(E5, kk[4][r], fmaf(E4, kk[3][r], fmaf(E3, kk[2][r],
               fmaf(E2, kk[1][r], E1 * kk[0][r]))));
    }
    stageA(p1); barrier_lgkm(); evalR(loadA0(), kk[5], uu[5]);

    f32x4 bu, epart, scv;
    #pragma unroll
    for (int r = 0; r < 4; ++r) {
      bu[r] = fmaf(B6, uu[5][r], Tbu[r]);
      synr[r] = fmaf(hcs[r], fmaf(B6, kk[5][r], Tbk[r]), syr[r]);
      epart[r] = fmaf(E6, kk[5][r], Te[r]);
      scv[r] = fmaf(1e-3f, fmaxf(fabsf(syr[r]), fabsf(synr[r])), 1e-6f);
      p1[r] = fmaf(hcs[r], bu[r], p_y[r]);
    }
    // early-stash: interp state known pre-k7; drains behind evalR's barriers
    if (w0 && cact) {
      #pragma unroll
      for (int r = 0; r < 4; ++r) {
        int o = (row0 + r) * SD + col;
        sY[o] = syr[r];
        sYN[o] = synr[r];
        sK1[o] = kk[0][r];
      }
    }
    stageA(p1); barrier_lgkm(); evalR(loadA0(), kk[6], uu[6]);   // k7 (FSAL)

    // stash k7 immediately: ds_writes drain under the DPP/controller VALU
    if (w0 && cact) {
      #pragma unroll
      for (int r = 0; r < 4; ++r) sK7[(row0 + r) * SD + col] = kk[6][r];
    }

    // ---- error norm: per-lane rr^2, DPP butterfly over the 16-group ----
    f32x4 rr2;
    #pragma unroll
    for (int r = 0; r < 4; ++r) {
      float err = hcs[r] * fmaf(E7, kk[6][r], epart[r]);
      float rr = err * __builtin_amdgcn_rcpf(scv[r]);   // ~1ulp vs exact divide
      rr2[r] = cact ? rr * rr : 0.0f;
    }
    #pragma unroll
    for (int r = 0; r < 4; ++r) {
      float v = rr2[r];
      v = dpp_add<0xB1>(v);    // xor1 (quad_perm 1,0,3,2)
      v = dpp_add<0x4E>(v);    // xor2 (quad_perm 2,3,0,1)
      v = dpp_add<0x124>(v);   // row_ror:4
      v = dpp_add<0x128>(v);   // row_ror:8
      rr2[r] = v;
    }

    // ---- controller: work in enorm^2 (sqrt-free; accept test equivalent) ----
    bool okr[4];
    #pragma unroll
    for (int r = 0; r < 4; ++r) {
      float e2 = rr2[r] * 0.2f;                 // enorm^2 = mean over 5 dims
      bool accept = e2 <= 1.0f;                 // == (enorm <= 1)
      float e2c = fmaxf(e2, 1e-20f);            // == max(enorm,1e-10)^2
      float factor = fminf(fmaxf(0.9f * __expf(-0.1f * __logf(e2c)), 0.2f), 10.0f);
      bool ok = accept && !dnr[r];
      okr[r] = ok;
      tcur[r] = ok ? tcur[r] + hcs[r] : tcur[r];
      hcur[r] = dnr[r] ? hcur[r] : hcs[r] * factor;
    }

    // ---- stash control (current step's tOldr/hcs/tcur) ----
    if (w0 && col == 0) {
      #pragma unroll
      for (int r = 0; r < 4; ++r) {
        int m2 = row0 + r;
        ctT[m2] = tOldr[r];
        ctH[m2] = hcs[r];
        ctN[m2] = tcur[r];
        ctO[m2] = okr[r] ? 1.0f : 0.0f;
      }
    }

    // ---- FSAL + state update (registers) ----
    #pragma unroll
    for (int r = 0; r < 4; ++r) {
      if (okr[r]) {
        syr[r] = synr[r];
        kk[0][r] = kk[6][r];
        uu[0][r] = uu[6][r];
        p_y[r] = fmaf(hcs[r], bu[r], p_y[r]);   // p_ynew = W1*ynew + b1 (recursed)
      }
    }

    // ---- next step's head + stage A (pre-barrier), then ONE merged barrier ----
    head();
    if (!alldone) {
      f32x4 pn;
      #pragma unroll
      for (int r = 0; r < 4; ++r) pn[r] = fmaf(hcs[r], A21 * uu[0][r], p_y[r]);
      stageA(pn);   // WAR on hl0 safe: last hl0 reads were >=2 barriers upstream
    }
    barrier_lgkm();   // orders stash + hl0 writes; interp fills the b1 shadow

    // early-issue next step's L2 A-frag reads: their LDS latency overlaps interp
    fNext = loadA0();

    // ---- cubic Hermite interpolation for save points in (t, t_next] ----
    {
      int tt = tid & 15;
      if (ctO[tt] != 0.0f) {
        float tOld = ctT[tt], hcv = ctH[tt], tNew = ctN[tt];
        float inv = __builtin_amdgcn_rcpf(fmaxf(hcv, 1e-12f));
        const int sb = tt * SD;
        f32x4 y4  = *(const f32x4*)(sY  + sb); float y4e  = sY [sb + 4];
        f32x4 yn4 = *(const f32x4*)(sYN + sb); float yn4e = sYN[sb + 4];
        f32x4 k14 = *(const f32x4*)(sK1 + sb); float k14e = sK1[sb + 4];
        f32x4 k74 = *(const f32x4*)(sK7 + sb); float k74e = sK7[sb + 4];
        k14 *= hcv; k14e *= hcv;
        k74 *= hcv; k74e *= hcv;
        #pragma unroll
        for (int q = 0; q < 4; ++q) {
          int n = 4 * ggl + q;
          float te = teq[q];
          if (te > tOld && te <= tNew + 1e-6f) {
            float sx = (te - tOld) * inv;
            float s2 = sx * sx, s3 = s2 * sx;
            float h00 = 2.f * s3 - 3.f * s2 + 1.f;
            float h10 = s3 - 2.f * s2 + sx;
            float h01 = -2.f * s3 + 3.f * s2;
            float h11 = s3 - s2;
            f32x4 o = h00 * y4 + h10 * k14 + h01 * yn4 + h11 * k74;
            float oe = h00 * y4e + h10 * k14e + h01 * yn4e + h11 * k74e;
            float* op = sOut + (n * kTraj + tt) * OSS;
            *(f32x4*)op = o;
            op[4] = oe;
          }
        }
      }
    }
  }

  // ---- flush LDS output accumulator to global, coalesced ----
  barrier_lgkm();
  {
    float* ob = out + (size_t)bid * (kTraj * kSave * kDim);
    for (int idx = tid; idx < kTraj * kSave * kDim; idx += kThreads) {
      int traj = idx / (kSave * kDim);
      int p = idx - traj * (kSave * kDim);
      int n = p / kDim;
      int d = p - n * kDim;
      ob[idx] = sOut[(n * kTraj + traj) * OSS + d];
    }
  }
}

}  // namespace

extern "C" void kernel_launch(void* const* d_in, const int* in_sizes, int n_in,
                              void* d_out, int out_size, void* d_ws, size_t ws_size,
                              hipStream_t stream) {
  const float* y0 = (const float*)d_in[0];
  const float* te = (const float*)d_in[1];
  const float* W1 = (const float*)d_in[2];
  const float* b1 = (const float*)d_in[3];
  const float* W2 = (const float*)d_in[4];
  const float* b2 = (const float*)d_in[5];
  const float* W3 = (const float*)d_in[6];
  const float* b3 = (const float*)d_in[7];
  const float* W4 = (const float*)d_in[8];
  const float* b4 = (const float*)d_in[9];
  float* out = (float*)d_out;

  const int batch = in_sizes[0] / kDim;      // 4096
  const int blocks = batch / kTraj;          // 256 blocks x 4 waves = 1 block/CU
  hipLaunchKernelGGL(node_tsit5_kernel, dim3(blocks), dim3(kThreads), 0, stream,
                     y0, te, W1, b1, W2, b2, W3, b3, W4, b4, out);
}